// Round 14
// baseline (6610.268 us; speedup 1.0000x reference)
//
#include <hip/hip_runtime.h>
#include <hip/hip_bf16.h>

#pragma clang fp contract(off)

#define NTH   1024      // 16 waves, 1 block per CU
#define PPT   16        // NTH*PPT == NPTS
#define NPTS  16384
#define BATCH 16
#define CFEAT 128
#define SMAX  4096
#define NWAVE (NTH / 64)

typedef __attribute__((ext_vector_type(2))) float f32x2;

// Pin into a VGPR (prevents rematerialization-from-global of Z).
__device__ __forceinline__ float f32_pin(float x) {
    asm volatile("" : "+v"(x));
    return x;
}

// ---------------------------------------------------------------------------
// FPS kernel, one block per batch.
// CORRECTNESS INVARIANTS (proven r0-r13; do not change):
//   * d  = fma(dz,dz, fma(dx,dx, dy*dy))   with dy*dy a separate v_mul
//   * dx = x + (-px) == x - px bitwise (r13-proven pk_add pattern)
//   * md = fminf(D[k], d)
//   * argmax: max value, ties -> LOWEST original point index (atomicMin gi)
//   * emission: idx[t] = last BEFORE the update pass
// r14 machinery:
//   * X,Y live in LDS as f32x2 pairs (128 KB): r10-r13 proved the allocator
//     caps this kernel at ~52 arch VGPRs and AGPR-parks any larger state
//     (v_accvgpr moves dominated issue). Register demand is now Z[16]+D[16]
//     +temps ~= 50 -> fits the granted budget, no AGPR traffic possible.
//   * interleaved mapping p = k*NTH+tid: ds_read_b64 bank = (2*tid)%32
//     (benign ~4-way); 16 independent read+math chains/thread let the
//     compiler hide LDS latency under VALU.
//   * per point: v_pk_add_f32 (dx,dy together) + v_sub + v_mul + 2 v_fma +
//     v_min + v_max = 7 VALU.
//   * winner coords: px,py from LDS (fast), pz from global (L2).
//   * r12's proven reduction: u32 shfl butterfly + LDS wave-max scan +
//     candidate rescan + atomicMin into rotating 4-slot cell, 2 barriers.
// ---------------------------------------------------------------------------
template <bool FUSED>
__global__ __launch_bounds__(NTH) void fps_kernel(const float* __restrict__ xyz,
                                                  const float* __restrict__ x,
                                                  int* __restrict__ idx_out,
                                                  float* __restrict__ out,
                                                  int S) {
    const int b    = blockIdx.x;
    const int tid  = threadIdx.x;
    const int wid  = tid >> 6;
    const int lane = tid & 63;
    const float* __restrict__ xb = xyz + (size_t)b * 3 * NPTS;

    __shared__ f32x2    s_xy[NPTS];          // 128 KB
    __shared__ unsigned s_vmax[NWAVE];
    __shared__ unsigned s_gi[4];
    __shared__ int      s_idx[FUSED ? SMAX : 1];

    float Z[PPT], D[PPT];
#pragma unroll
    for (int k = 0; k < PPT; ++k) {
        const int p = k * NTH + tid;
        f32x2 v;
        v.x = xb[p];
        v.y = xb[NPTS + p];
        s_xy[p] = v;
        Z[k] = f32_pin(xb[2 * NPTS + p]);
        D[k] = INFINITY;
    }
    if (tid == 0) { s_gi[0] = s_gi[1] = s_gi[2] = s_gi[3] = 0xFFFFFFFFu; }
    __syncthreads();

    int   last = 0;
    float px = xb[0], py = xb[NPTS], pz = xb[2 * NPTS];

    for (int t = 0; t < S; ++t) {
        if (tid == 0) {
            if (FUSED) s_idx[t] = last;
            else       idx_out[b * S + t] = last;
        }

        f32x2 npxy;
        npxy.x = -px;
        npxy.y = -py;

        // ---- update pass: LDS xy + reg Z/D, 7 VALU + 1 ds_read per point
        float best = -INFINITY;
#pragma unroll
        for (int k = 0; k < PPT; ++k) {
            const f32x2 xy = s_xy[k * NTH + tid];
            f32x2 dxy;
            asm("v_pk_add_f32 %0, %1, %2" : "=v"(dxy) : "v"(xy), "v"(npxy));
            const float dz = Z[k] - pz;
            const float d  = __builtin_fmaf(dz, dz,
                               __builtin_fmaf(dxy.x, dxy.x, dxy.y * dxy.y));
            const float md = fminf(D[k], d);
            D[k] = md;
            best = fmaxf(best, md);
        }
        const unsigned mybits = __float_as_uint(best);  // d>=0: u32 order == f32 order

        // ---- wave max: u32 butterfly
        unsigned bu = mybits;
#pragma unroll
        for (int off = 32; off >= 1; off >>= 1) {
            const unsigned o = __shfl_xor(bu, off);
            bu = (o > bu) ? o : bu;
        }
        if (lane == 0) s_vmax[wid] = bu;
        if (tid == 0)  s_gi[(t + 2) & 3] = 0xFFFFFFFFu;   // rotate-init future slot
        __syncthreads();                                   // B1

        // ---- block max (broadcast LDS reads)
        unsigned vb = s_vmax[0];
#pragma unroll
        for (int w = 1; w < NWAVE; ++w) {
            const unsigned vw = s_vmax[w];
            vb = (vw > vb) ? vw : vb;
        }

        // ---- index resolve: only candidate lanes (~1-2 per block) pay
        if (mybits == vb) {
            int kk = PPT - 1;
#pragma unroll
            for (int k = PPT - 1; k >= 0; --k)
                if (__float_as_uint(D[k]) == mybits) kk = k;   // lowest k => lowest gi
            atomicMin(&s_gi[t & 3], (unsigned)(kk * NTH + tid));
        }
        __syncthreads();                                   // B2

        last = (int)s_gi[t & 3];
        // winner coords: x,y from LDS (fast), z from global (L2-resident)
        const f32x2 pxy = s_xy[last];
        px = pxy.x;
        py = pxy.y;
        pz = xb[2 * NPTS + last];
    }

    if (FUSED) {
        __syncthreads();
        for (int i = tid; i < CFEAT * S; i += NTH) {
            const int c = i / S, s = i - c * S;
            const long r = (long)b * CFEAT + c;
            out[r * S + s] = x[r * NPTS + s_idx[s]];
        }
        const long base = (long)BATCH * CFEAT * S;
        for (int i = tid; i < 3 * S; i += NTH) {
            const int c = i / S, s = i - c * S;
            const long r = (long)b * 3 + c;
            out[base + r * S + s] = xyz[r * NPTS + s_idx[s]];
        }
    }
}

// ---------------------------------------------------------------------------
// Gather kernel (full-chip): out = concat( x_s [B][C][S], xyz_s [B][3][S] ).
// ---------------------------------------------------------------------------
__global__ void gather_kernel(const float* __restrict__ x,
                              const float* __restrict__ xyz,
                              const int* __restrict__ idx,
                              float* __restrict__ out,
                              int S) {
    const long nxs   = (long)BATCH * CFEAT * S;
    const long total = nxs + (long)BATCH * 3 * S;
    for (long i = (long)blockIdx.x * blockDim.x + threadIdx.x; i < total;
         i += (long)gridDim.x * blockDim.x) {
        if (i < nxs) {
            const int s  = (int)(i % S);
            const long r = i / S;            // b*C + c
            const int b  = (int)(r / CFEAT);
            const int p  = idx[b * S + s];
            out[i] = x[r * NPTS + p];
        } else {
            const long j = i - nxs;
            const int s  = (int)(j % S);
            const long r = j / S;            // b*3 + c
            const int b  = (int)(r / 3);
            const int p  = idx[b * S + s];
            out[i] = xyz[r * NPTS + p];
        }
    }
}

extern "C" void kernel_launch(void* const* d_in, const int* in_sizes, int n_in,
                              void* d_out, int out_size, void* d_ws, size_t ws_size,
                              hipStream_t stream) {
    const float* x   = nullptr;   // [B, C, N]
    const float* xyz = nullptr;   // [B, 3, N]
    for (int i = 0; i < n_in; ++i) {
        if (in_sizes[i] == BATCH * CFEAT * NPTS)  x   = (const float*)d_in[i];
        else if (in_sizes[i] == BATCH * 3 * NPTS) xyz = (const float*)d_in[i];
    }
    float* out = (float*)d_out;
    const int S = out_size / (BATCH * (CFEAT + 3));

    const size_t need = (size_t)BATCH * (size_t)S * sizeof(int);
    if (ws_size >= need && d_ws != nullptr) {
        int* idx = (int*)d_ws;
        fps_kernel<false><<<BATCH, NTH, 0, stream>>>(xyz, nullptr, idx, nullptr, S);
        gather_kernel<<<2048, 256, 0, stream>>>(x, xyz, idx, out, S);
    } else {
        fps_kernel<true><<<BATCH, NTH, 0, stream>>>(xyz, x, nullptr, out, S);
    }
}

// Round 15
// 6215.268 us; speedup vs baseline: 1.0636x; 1.0636x over previous
//
#include <hip/hip_runtime.h>
#include <hip/hip_bf16.h>

#pragma clang fp contract(off)

#define NTH   1024      // 16 waves, 1 block per CU
#define PPT   16        // NTH*PPT == NPTS
#define NPTS  16384
#define BATCH 16
#define CFEAT 128
#define SMAX  4096
#define NWAVE (NTH / 64)
// Prune margin: skip requires lb*PRUNE_C >= waveMaxD. Error budget: lb_f32
// over-estimates true bbox dist^2 by <= 2^-21 rel; d (FMA form) under-
// estimates true dist^2 by <= 2^-21.4 rel. 5e-6 margin is ~7x that -> a skip
// is PROVABLY a bitwise no-op on every skipped D[k].
#define PRUNE_C 0.999995f

__device__ __forceinline__ unsigned spread3(unsigned v) {
    v &= 0x3FFu;
    v = (v | (v << 16)) & 0x030000FFu;
    v = (v | (v << 8))  & 0x0300F00Fu;
    v = (v | (v << 4))  & 0x030C30C3u;
    v = (v | (v << 2))  & 0x09249249u;
    return v;
}
__device__ __forceinline__ unsigned qz10(float v) {
    int q = (int)((v + 6.0f) * (1023.0f / 12.0f));   // layout-only; clamp below
    q = q < 0 ? 0 : (q > 1023 ? 1023 : q);
    return (unsigned)q;
}

// ---------------------------------------------------------------------------
// FPS kernel, one block per batch.
// CORRECTNESS INVARIANTS (proven r0-r14; do not change):
//   * d  = fma(dz,dz, fma(dx,dx, dy*dy))   [XLA contraction form]
//   * md = fminf(D[k], d)
//   * argmax: max value, ties -> LOWEST ORIGINAL point index (atomicMin)
//   * emission: idx[t] = last BEFORE the update pass
// r15 machinery (QuickFPS-style wave pruning, exactness-safe):
//   * one-time: morton keys -> LDS bitonic sort (key,origIdx). Sort affects
//     LAYOUT only; any permutation is correct (perm kept in s_val for the
//     tie-break + output). Coords gathered into registers; per-wave 3D bbox.
//   * per iter: wave skips update+butterfly iff lb(pick,bbox)*PRUNE_C >=
//     cached waveMax(D)  (uniform branch). Skipped updates are provable
//     bitwise no-ops; pick's own wave can't skip (lb=0). Cached myBits /
//     wBest stay valid across skips (D unchanged).
//   * r12's reduction: publish wave max -> B1 -> block max -> candidate
//     threads rescan D + atomicMin ORIGINAL gi (rotating slot) -> B2 ->
//     uniform L2 coord fetch.
// ---------------------------------------------------------------------------
template <bool FUSED>
__global__ __launch_bounds__(NTH) void fps_kernel(const float* __restrict__ xyz,
                                                  const float* __restrict__ x,
                                                  int* __restrict__ idx_out,
                                                  float* __restrict__ out,
                                                  int S) {
    const int b    = blockIdx.x;
    const int tid  = threadIdx.x;
    const int wid  = tid >> 6;
    const int lane = tid & 63;
    const float* __restrict__ xb = xyz + (size_t)b * 3 * NPTS;

    __shared__ unsigned s_key[NPTS];     // 64 KB (sort keys)
    __shared__ unsigned s_val[NPTS];     // 64 KB (permutation: sorted pos -> orig idx)
    __shared__ unsigned s_vmax[NWAVE];
    __shared__ unsigned s_gi[4];
    __shared__ int      s_idx[FUSED ? SMAX : 1];

    // ---- phase 0a: morton keys (coalesced)
    for (int k = 0; k < PPT; ++k) {
        const int p = k * NTH + tid;
        const float xx = xb[p], yy = xb[NPTS + p], zz = xb[2 * NPTS + p];
        s_key[p] = (spread3(qz10(xx)) << 2) | (spread3(qz10(yy)) << 1) | spread3(qz10(zz));
        s_val[p] = (unsigned)p;
    }
    if (tid == 0) { s_gi[0] = s_gi[1] = s_gi[2] = s_gi[3] = 0xFFFFFFFFu; }

    // ---- phase 0b: bitonic sort (key,val), 105 phases
    for (int len = 2; len <= NPTS; len <<= 1) {
        for (int stride = len >> 1; stride > 0; stride >>= 1) {
            __syncthreads();
            for (int i = tid; i < NPTS / 2; i += NTH) {
                const int pos = 2 * i - (i & (stride - 1));
                const int opp = pos + stride;
                const bool asc = ((pos & len) == 0);
                const unsigned ka = s_key[pos], kb = s_key[opp];
                if (asc ? (ka > kb) : (ka < kb)) {
                    s_key[pos] = kb; s_key[opp] = ka;
                    const unsigned va = s_val[pos], vv = s_val[opp];
                    s_val[pos] = vv; s_val[opp] = va;
                }
            }
        }
    }
    __syncthreads();

    // ---- phase 0c: gather owned sorted points into registers + wave bbox
    float X[PPT], Y[PPT], Z[PPT], D[PPT];
    const int base = tid * PPT;
    float bxl =  INFINITY, byl =  INFINITY, bzl =  INFINITY;
    float bxh = -INFINITY, byh = -INFINITY, bzh = -INFINITY;
#pragma unroll
    for (int k = 0; k < PPT; ++k) {
        const unsigned gi = s_val[base + k];
        const float xx = xb[gi], yy = xb[NPTS + gi], zz = xb[2 * NPTS + gi];
        X[k] = xx; Y[k] = yy; Z[k] = zz; D[k] = INFINITY;
        bxl = fminf(bxl, xx); bxh = fmaxf(bxh, xx);
        byl = fminf(byl, yy); byh = fmaxf(byh, yy);
        bzl = fminf(bzl, zz); bzh = fmaxf(bzh, zz);
    }
#pragma unroll
    for (int off = 32; off >= 1; off >>= 1) {   // wave-union bbox (uniform after)
        bxl = fminf(bxl, __shfl_xor(bxl, off)); bxh = fmaxf(bxh, __shfl_xor(bxh, off));
        byl = fminf(byl, __shfl_xor(byl, off)); byh = fmaxf(byh, __shfl_xor(byh, off));
        bzl = fminf(bzl, __shfl_xor(bzl, off)); bzh = fmaxf(bzh, __shfl_xor(bzh, off));
    }

    int      last   = 0;
    float    px = xb[0], py = xb[NPTS], pz = xb[2 * NPTS];
    float    wBest  = INFINITY;   // cached wave max (uniform); valid across skips
    unsigned myBits = 0;          // cached thread max bits;  valid across skips

    for (int t = 0; t < S; ++t) {
        if (tid == 0) {
            if (FUSED) s_idx[t] = last;
            else       idx_out[b * S + t] = last;
        }

        // ---- wave-level prune test (all operands wave-uniform)
        const float gx = fmaxf(fmaxf(bxl - px, px - bxh), 0.0f);
        const float gy = fmaxf(fmaxf(byl - py, py - byh), 0.0f);
        const float gz = fmaxf(fmaxf(bzl - pz, pz - bzh), 0.0f);
        const float lb = gx * gx + gy * gy + gz * gz;

        if (!(lb * PRUNE_C >= wBest)) {
            // ---- full update + wave butterfly (only when bbox can matter)
            float bestv = -INFINITY;
#pragma unroll
            for (int k = 0; k < PPT; ++k) {
                const float dx = X[k] - px, dy = Y[k] - py, dz = Z[k] - pz;
                const float d  = __builtin_fmaf(dz, dz, __builtin_fmaf(dx, dx, dy * dy));
                const float md = fminf(D[k], d);
                D[k] = md;
                bestv = fmaxf(bestv, md);
            }
            myBits = __float_as_uint(bestv);
            unsigned bu = myBits;
#pragma unroll
            for (int off = 32; off >= 1; off >>= 1) {
                const unsigned o = __shfl_xor(bu, off);
                bu = (o > bu) ? o : bu;
            }
            wBest = __uint_as_float(bu);
        }
        if (lane == 0) s_vmax[wid] = __float_as_uint(wBest);
        if (tid == 0)  s_gi[(t + 2) & 3] = 0xFFFFFFFFu;       // rotate-init future slot
        __syncthreads();                                       // B1

        // ---- block max (broadcast LDS reads)
        unsigned vb = s_vmax[0];
#pragma unroll
        for (int w = 1; w < NWAVE; ++w) {
            const unsigned vw = s_vmax[w];
            vb = (vw > vb) ? vw : vb;
        }

        // ---- candidates resolve lowest ORIGINAL index (rare path)
        if (myBits == vb) {
            unsigned g = 0xFFFFFFFFu;
#pragma unroll
            for (int k = 0; k < PPT; ++k) {
                if (__float_as_uint(D[k]) == vb) {
                    const unsigned gg = s_val[base + k];   // original index
                    g = (gg < g) ? gg : g;
                }
            }
            atomicMin(&s_gi[t & 3], g);
        }
        __syncthreads();                                       // B2

        last = (int)s_gi[t & 3];
        px = xb[last]; py = xb[NPTS + last]; pz = xb[2 * NPTS + last];
    }

    if (FUSED) {
        __syncthreads();
        for (int i = tid; i < CFEAT * S; i += NTH) {
            const int c = i / S, s = i - c * S;
            const long r = (long)b * CFEAT + c;
            out[r * S + s] = x[r * NPTS + s_idx[s]];
        }
        const long base2 = (long)BATCH * CFEAT * S;
        for (int i = tid; i < 3 * S; i += NTH) {
            const int c = i / S, s = i - c * S;
            const long r = (long)b * 3 + c;
            out[base2 + r * S + s] = xyz[r * NPTS + s_idx[s]];
        }
    }
}

// ---------------------------------------------------------------------------
// Gather kernel (full-chip): out = concat( x_s [B][C][S], xyz_s [B][3][S] ).
// ---------------------------------------------------------------------------
__global__ void gather_kernel(const float* __restrict__ x,
                              const float* __restrict__ xyz,
                              const int* __restrict__ idx,
                              float* __restrict__ out,
                              int S) {
    const long nxs   = (long)BATCH * CFEAT * S;
    const long total = nxs + (long)BATCH * 3 * S;
    for (long i = (long)blockIdx.x * blockDim.x + threadIdx.x; i < total;
         i += (long)gridDim.x * blockDim.x) {
        if (i < nxs) {
            const int s  = (int)(i % S);
            const long r = i / S;            // b*C + c
            const int b  = (int)(r / CFEAT);
            const int p  = idx[b * S + s];
            out[i] = x[r * NPTS + p];
        } else {
            const long j = i - nxs;
            const int s  = (int)(j % S);
            const long r = j / S;            // b*3 + c
            const int b  = (int)(r / 3);
            const int p  = idx[b * S + s];
            out[i] = xyz[r * NPTS + p];
        }
    }
}

extern "C" void kernel_launch(void* const* d_in, const int* in_sizes, int n_in,
                              void* d_out, int out_size, void* d_ws, size_t ws_size,
                              hipStream_t stream) {
    const float* x   = nullptr;   // [B, C, N]
    const float* xyz = nullptr;   // [B, 3, N]
    for (int i = 0; i < n_in; ++i) {
        if (in_sizes[i] == BATCH * CFEAT * NPTS)  x   = (const float*)d_in[i];
        else if (in_sizes[i] == BATCH * 3 * NPTS) xyz = (const float*)d_in[i];
    }
    float* out = (float*)d_out;
    const int S = out_size / (BATCH * (CFEAT + 3));

    const size_t need = (size_t)BATCH * (size_t)S * sizeof(int);
    if (ws_size >= need && d_ws != nullptr) {
        int* idx = (int*)d_ws;
        fps_kernel<false><<<BATCH, NTH, 0, stream>>>(xyz, nullptr, idx, nullptr, S);
        gather_kernel<<<2048, 256, 0, stream>>>(x, xyz, idx, out, S);
    } else {
        fps_kernel<true><<<BATCH, NTH, 0, stream>>>(xyz, x, nullptr, out, S);
    }
}

// Round 16
// 5701.710 us; speedup vs baseline: 1.1593x; 1.0901x over previous
//
#include <hip/hip_runtime.h>
#include <hip/hip_bf16.h>

#pragma clang fp contract(off)

#define NTH   1024      // 16 waves, 1 block per CU
#define PPT   16        // NTH*PPT == NPTS
#define NPTS  16384
#define BATCH 16
#define CFEAT 128
#define SMAX  4096
#define NWAVE (NTH / 64)
// Prune margin (r15-proven exact): skip iff lb*PRUNE_C >= waveMaxD.
#define PRUNE_C 0.999995f
// LDS index swizzle for the bitonic sort: breaks power-of-2 stride bank
// aliasing (u64 elements conflict at stride>=16). Bijective => sort-correct.
#define NPAD(i) ((i) + ((i) >> 4))

__device__ __forceinline__ unsigned spread3(unsigned v) {
    v &= 0x3FFu;
    v = (v | (v << 16)) & 0x030000FFu;
    v = (v | (v << 8))  & 0x0300F00Fu;
    v = (v | (v << 4))  & 0x030C30C3u;
    v = (v | (v << 2))  & 0x09249249u;
    return v;
}
__device__ __forceinline__ unsigned qz10(float v) {
    int q = (int)((v + 6.0f) * (1023.0f / 12.0f));   // layout-only
    q = q < 0 ? 0 : (q > 1023 ? 1023 : q);
    return (unsigned)q;
}

// ---------------------------------------------------------------------------
// FPS kernel, one block per batch.
// CORRECTNESS INVARIANTS (proven r0-r15; do not change):
//   * d  = fma(dz,dz, fma(dx,dx, dy*dy))   [XLA contraction form]
//   * md = fminf(D[k], d)
//   * argmax: max value, ties -> LOWEST ORIGINAL point index
//   * emission: idx[t] = last BEFORE the update pass
// r16 machinery:
//   * packed-u64 bitonic sort (morton<<32|origIdx) with NPAD swizzle:
//     r15's 1.83M bank conflicts (~750us) -> ~0. Identical control flow.
//   * ONE barrier/iter: candidates atomicMax a rotating LDS u64 slot with
//     pack = valbits<<32 | (0xFFFFFFFF - origIdx)  => integer max == (max
//     value, then min ORIGINAL index) — exactly the frozen total order.
//     Skipped waves re-issue their CACHED pack (D unchanged => still valid).
//     Slot (t+2)&3 re-inited each iter: distance-2 rotation (r10-proven).
//   * wave bbox pruning on sorted chunks (r15-proven margin).
//   * original indices kept in registers as 8x packed u16 pairs.
// ---------------------------------------------------------------------------
template <bool FUSED>
__global__ __launch_bounds__(NTH) void fps_kernel(const float* __restrict__ xyz,
                                                  const float* __restrict__ x,
                                                  int* __restrict__ idx_out,
                                                  float* __restrict__ out,
                                                  int S) {
    const int b    = blockIdx.x;
    const int tid  = threadIdx.x;
    const int wid  = tid >> 6;
    const int lane = tid & 63;
    const float* __restrict__ xb = xyz + (size_t)b * 3 * NPTS;

    __shared__ unsigned long long s_kv[NPTS + (NPTS >> 4)];  // 139.3 KB (swizzled)
    __shared__ unsigned long long s_slot[4];
    __shared__ int s_idx[FUSED ? SMAX : 1];

    // ---- phase 0a: packed morton keys (coalesced reads)
    for (int k = 0; k < PPT; ++k) {
        const int p = k * NTH + tid;
        const float xx = xb[p], yy = xb[NPTS + p], zz = xb[2 * NPTS + p];
        const unsigned m = (spread3(qz10(xx)) << 2) | (spread3(qz10(yy)) << 1)
                         | spread3(qz10(zz));
        s_kv[NPAD(p)] = ((unsigned long long)m << 32) | (unsigned)p;
    }
    if (tid == 0) { s_slot[0] = s_slot[1] = s_slot[2] = s_slot[3] = 0ull; }

    // ---- phase 0b: bitonic sort on packed u64 (r15-proven control flow)
    for (int len = 2; len <= NPTS; len <<= 1) {
        for (int stride = len >> 1; stride > 0; stride >>= 1) {
            __syncthreads();
            for (int i = tid; i < NPTS / 2; i += NTH) {
                const int pos = 2 * i - (i & (stride - 1));
                const int opp = pos + stride;
                const bool asc = ((pos & len) == 0);
                const unsigned long long a = s_kv[NPAD(pos)];
                const unsigned long long c = s_kv[NPAD(opp)];
                if (asc ? (a > c) : (a < c)) {
                    s_kv[NPAD(pos)] = c;
                    s_kv[NPAD(opp)] = a;
                }
            }
        }
    }
    __syncthreads();

    // ---- phase 0c: gather owned sorted points into registers + wave bbox
    float X[PPT], Y[PPT], Z[PPT], D[PPT];
    unsigned VI[PPT / 2];                       // orig indices, 2x u16 per u32
    const int base = tid * PPT;
    float bxl =  INFINITY, byl =  INFINITY, bzl =  INFINITY;
    float bxh = -INFINITY, byh = -INFINITY, bzh = -INFINITY;
#pragma unroll
    for (int k = 0; k < PPT; ++k) {
        const unsigned gi = (unsigned)(s_kv[NPAD(base + k)] & 0xFFFFFFFFull);
        const float xx = xb[gi], yy = xb[NPTS + gi], zz = xb[2 * NPTS + gi];
        X[k] = xx; Y[k] = yy; Z[k] = zz; D[k] = INFINITY;
        if ((k & 1) == 0) VI[k >> 1] = gi;
        else              VI[k >> 1] |= (gi << 16);
        bxl = fminf(bxl, xx); bxh = fmaxf(bxh, xx);
        byl = fminf(byl, yy); byh = fmaxf(byh, yy);
        bzl = fminf(bzl, zz); bzh = fmaxf(bzh, zz);
    }
#pragma unroll
    for (int off = 32; off >= 1; off >>= 1) {   // wave-union bbox (uniform after)
        bxl = fminf(bxl, __shfl_xor(bxl, off)); bxh = fmaxf(bxh, __shfl_xor(bxh, off));
        byl = fminf(byl, __shfl_xor(byl, off)); byh = fmaxf(byh, __shfl_xor(byh, off));
        bzl = fminf(bzl, __shfl_xor(bzl, off)); bzh = fmaxf(bzh, __shfl_xor(bzh, off));
    }

    int      last   = 0;
    float    px = xb[0], py = xb[NPTS], pz = xb[2 * NPTS];
    float    wBest  = INFINITY;      // cached wave max (uniform across skips)
    unsigned long long myPack = 0;   // cached candidate contribution (per lane)

    for (int t = 0; t < S; ++t) {
        if (tid == 0) {
            if (FUSED) s_idx[t] = last;
            else       idx_out[b * S + t] = last;
        }

        // ---- wave-level prune test (uniform operands)
        const float gx = fmaxf(fmaxf(bxl - px, px - bxh), 0.0f);
        const float gy = fmaxf(fmaxf(byl - py, py - byh), 0.0f);
        const float gz = fmaxf(fmaxf(bzl - pz, pz - bzh), 0.0f);
        const float lb = gx * gx + gy * gy + gz * gz;

        if (!(lb * PRUNE_C >= wBest)) {
            // ---- full update + wave butterfly (only when bbox can matter)
            float bestv = -INFINITY;
#pragma unroll
            for (int k = 0; k < PPT; ++k) {
                const float dx = X[k] - px, dy = Y[k] - py, dz = Z[k] - pz;
                const float d  = __builtin_fmaf(dz, dz, __builtin_fmaf(dx, dx, dy * dy));
                const float md = fminf(D[k], d);
                D[k] = md;
                bestv = fmaxf(bestv, md);
            }
            const unsigned mybits = __float_as_uint(bestv);
            unsigned bu = mybits;
#pragma unroll
            for (int off = 32; off >= 1; off >>= 1) {
                const unsigned o = __shfl_xor(bu, off);
                bu = (o > bu) ? o : bu;
            }
            wBest = __uint_as_float(bu);

            myPack = 0;
            if (mybits == bu) {                 // candidate lane (~1 per wave)
                unsigned mo = 0xFFFFFFFFu;      // lowest ORIGINAL idx at max
#pragma unroll
                for (int k = 0; k < PPT; ++k) {
                    if (__float_as_uint(D[k]) == mybits) {
                        const unsigned gg = (VI[k >> 1] >> ((k & 1) * 16)) & 0xFFFFu;
                        mo = (gg < mo) ? gg : mo;
                    }
                }
                myPack = ((unsigned long long)mybits << 32)
                       | (unsigned long long)(0xFFFFFFFFu - mo);
            }
        }
        // candidates (fresh or cached from skipped iterations) publish
        if (myPack) atomicMax(&s_slot[t & 3], myPack);
        if (tid == 0) s_slot[(t + 2) & 3] = 0ull;      // distance-2 rotate-init
        __syncthreads();                                // the ONE barrier

        const unsigned long long win = s_slot[t & 3];
        last = (int)(0xFFFFFFFFu - (unsigned)(win & 0xFFFFFFFFull));
        px = xb[last]; py = xb[NPTS + last]; pz = xb[2 * NPTS + last];
    }

    if (FUSED) {
        __syncthreads();
        for (int i = tid; i < CFEAT * S; i += NTH) {
            const int c = i / S, s = i - c * S;
            const long r = (long)b * CFEAT + c;
            out[r * S + s] = x[r * NPTS + s_idx[s]];
        }
        const long base2 = (long)BATCH * CFEAT * S;
        for (int i = tid; i < 3 * S; i += NTH) {
            const int c = i / S, s = i - c * S;
            const long r = (long)b * 3 + c;
            out[base2 + r * S + s] = xyz[r * NPTS + s_idx[s]];
        }
    }
}

// ---------------------------------------------------------------------------
// Gather kernel (full-chip): out = concat( x_s [B][C][S], xyz_s [B][3][S] ).
// ---------------------------------------------------------------------------
__global__ void gather_kernel(const float* __restrict__ x,
                              const float* __restrict__ xyz,
                              const int* __restrict__ idx,
                              float* __restrict__ out,
                              int S) {
    const long nxs   = (long)BATCH * CFEAT * S;
    const long total = nxs + (long)BATCH * 3 * S;
    for (long i = (long)blockIdx.x * blockDim.x + threadIdx.x; i < total;
         i += (long)gridDim.x * blockDim.x) {
        if (i < nxs) {
            const int s  = (int)(i % S);
            const long r = i / S;            // b*C + c
            const int b  = (int)(r / CFEAT);
            const int p  = idx[b * S + s];
            out[i] = x[r * NPTS + p];
        } else {
            const long j = i - nxs;
            const int s  = (int)(j % S);
            const long r = j / S;            // b*3 + c
            const int b  = (int)(r / 3);
            const int p  = idx[b * S + s];
            out[i] = xyz[r * NPTS + p];
        }
    }
}

extern "C" void kernel_launch(void* const* d_in, const int* in_sizes, int n_in,
                              void* d_out, int out_size, void* d_ws, size_t ws_size,
                              hipStream_t stream) {
    const float* x   = nullptr;   // [B, C, N]
    const float* xyz = nullptr;   // [B, 3, N]
    for (int i = 0; i < n_in; ++i) {
        if (in_sizes[i] == BATCH * CFEAT * NPTS)  x   = (const float*)d_in[i];
        else if (in_sizes[i] == BATCH * 3 * NPTS) xyz = (const float*)d_in[i];
    }
    float* out = (float*)d_out;
    const int S = out_size / (BATCH * (CFEAT + 3));

    const size_t need = (size_t)BATCH * (size_t)S * sizeof(int);
    if (ws_size >= need && d_ws != nullptr) {
        int* idx = (int*)d_ws;
        fps_kernel<false><<<BATCH, NTH, 0, stream>>>(xyz, nullptr, idx, nullptr, S);
        gather_kernel<<<2048, 256, 0, stream>>>(x, xyz, idx, out, S);
    } else {
        fps_kernel<true><<<BATCH, NTH, 0, stream>>>(xyz, x, nullptr, out, S);
    }
}